// Round 15
// baseline (74.709 us; speedup 1.0000x reference)
//
#include <hip/hip_runtime.h>

// out[2048,64] = inputs[2048,2000] @ emb[2000,64] (fp32) via bf16 MFMA.
// K0: pre-pack E into MFMA B-fragment order (bf16, 256 KB ws) [R14-validated].
// K1: FUSED, no partials/no K2. 512 blocks x 4 rows. Block stages its 4 A rows
//     in LDS bf16 (each wave stages one row, coalesced). Waves split K: wave w
//     does K-steps [16w,16w+16) x all 4 col-tiles, B-frags direct from ef
//     (1KB/wave coalesced, L2-hot). Cross-wave reduce in LDS -> out.
//     MFMA A-rows 4..15 are garbage (not zeroed): C rows depend only on their
//     own A row; we only store C rows 0..3.

#define Bn 2048
#define Vn 2000
#define Dn 64
#define NKS 64                // K-steps of 32 (64*32 = 2048, zero-padded)
#define LSTR2 2056            // A LDS row stride (shorts); k-cols 2000..2047 zeroed

typedef __attribute__((ext_vector_type(8))) short bf16x8;
typedef __attribute__((ext_vector_type(4))) float f32x4;

__device__ inline unsigned short bf16r(float x) {
    union { float f; unsigned u; } c; c.f = x;
    return (unsigned short)((c.u + 0x8000u) >> 16);
}
__device__ inline unsigned pk2(float a, float b) {
    return ((unsigned)bf16r(b) << 16) | bf16r(a);
}

// ---- K0: E (2000x64 f32) -> Efrag[NKS][4][64] x 16B (R14 code, validated) ----
__global__ __launch_bounds__(256)
void efrag_k(const float* __restrict__ E, uint4* __restrict__ ef) {
    const int ks   = blockIdx.x;            // 0..63
    const int ct   = threadIdx.x >> 6;      // 0..3
    const int lane = threadIdx.x & 63;
    const int d    = ct * 16 + (lane & 15);
    const int kb   = ks * 32 + (lane >> 4) * 8;
    unsigned short h[8];
#pragma unroll
    for (int j = 0; j < 8; ++j) {
        const int gk = kb + j;
        h[j] = (gk < Vn) ? bf16r(E[(size_t)gk * Dn + d]) : (unsigned short)0;
    }
    uint4 v;
    v.x = (unsigned)h[0] | ((unsigned)h[1] << 16);
    v.y = (unsigned)h[2] | ((unsigned)h[3] << 16);
    v.z = (unsigned)h[4] | ((unsigned)h[5] << 16);
    v.w = (unsigned)h[6] | ((unsigned)h[7] << 16);
    ef[((size_t)ks * 4 + ct) * 64 + lane] = v;
}

// ---- K1: fused GEMM, split-K across waves, LDS reduce ----
__global__ __launch_bounds__(256)
void embw_fused(const float* __restrict__ A, const bf16x8* __restrict__ ef,
                float* __restrict__ out) {
    __shared__ unsigned short Al[4][LSTR2];     // 4 A rows, bf16
    __shared__ float red[4][4][64];             // [wave][row][col] partials

    const int t    = threadIdx.x;
    const int lane = t & 63;
    const int w    = t >> 6;
    const int r0   = blockIdx.x * 4;

    // ---- stage: wave w stages A row w (500 float4s over 64 lanes) ----
    {
        const float* src = A + (size_t)(r0 + w) * Vn;
#pragma unroll 1
        for (int k4 = lane; k4 < Vn / 4; k4 += 64) {
            float4 v = *(const float4*)&src[k4 * 4];
            *(uint2*)&Al[w][k4 * 4] = make_uint2(pk2(v.x, v.y), pk2(v.z, v.w));
        }
        if (lane < 24)                            // zero k = 2000..2047
            *(unsigned*)&Al[w][Vn + lane * 2] = 0u;
    }
    __syncthreads();

    const int fr = lane & 15;
    const int fk = (lane >> 4) * 8;
    const unsigned short* arow = Al[fr & 3];      // rows 4..15 -> alias 0..3 (garbage ok)

    f32x4 acc0 = {0.f,0.f,0.f,0.f}, acc1 = {0.f,0.f,0.f,0.f};
    f32x4 acc2 = {0.f,0.f,0.f,0.f}, acc3 = {0.f,0.f,0.f,0.f};

    // ---- wave w: K-steps [16w, 16w+16), all 4 col-tiles ----
#pragma unroll 4
    for (int i = 0; i < 16; ++i) {
        const int ks = w * 16 + i;
        const size_t eb = (size_t)ks * 256 + lane;
        bf16x8 af = *(const bf16x8*)&arow[ks * 32 + fk];
        bf16x8 b0 = ef[eb +   0];
        bf16x8 b1 = ef[eb +  64];
        bf16x8 b2 = ef[eb + 128];
        bf16x8 b3 = ef[eb + 192];
        acc0 = __builtin_amdgcn_mfma_f32_16x16x32_bf16(af, b0, acc0, 0, 0, 0);
        acc1 = __builtin_amdgcn_mfma_f32_16x16x32_bf16(af, b1, acc1, 0, 0, 0);
        acc2 = __builtin_amdgcn_mfma_f32_16x16x32_bf16(af, b2, acc2, 0, 0, 0);
        acc3 = __builtin_amdgcn_mfma_f32_16x16x32_bf16(af, b3, acc3, 0, 0, 0);
    }

    // ---- cross-wave reduce: only lanes 0..15 hold real rows (0..3) ----
    if (lane < 16) {
#pragma unroll
        for (int q = 0; q < 4; ++q) {
            red[w][q][ 0 + fr] = acc0[q];
            red[w][q][16 + fr] = acc1[q];
            red[w][q][32 + fr] = acc2[q];
            red[w][q][48 + fr] = acc3[q];
        }
    }
    __syncthreads();
    {
        const int row = t >> 6;                   // 0..3
        const int col = t & 63;
        float s = red[0][row][col] + red[1][row][col]
                + red[2][row][col] + red[3][row][col];
        out[(size_t)(r0 + row) * Dn + col] = s;   // coalesced 256B/row
    }
}

extern "C" void kernel_launch(void* const* d_in, const int* in_sizes, int n_in,
                              void* d_out, int out_size, void* d_ws, size_t ws_size,
                              hipStream_t stream) {
    const float* in  = (const float*)d_in[0];   // (2048, 2000) fp32
    const float* emb = (const float*)d_in[1];   // (2000, 64)  fp32
    float* out = (float*)d_out;                 // (2048, 64)  fp32

    uint4* efrag = (uint4*)d_ws;                // 256 KB

    efrag_k<<<NKS, 256, 0, stream>>>(emb, efrag);
    embw_fused<<<Bn / 4, 256, 0, stream>>>(in, (const bf16x8*)efrag, out);
}